// Round 7
// baseline (213.756 us; speedup 1.0000x reference)
//
#include <hip/hip_runtime.h>

#define NNODES 50000
#define NEDGES 800000
#define NTILES 3125      // 50000 / 16
#define CAP    64        // bucket capacity per dst node (Poisson(16); P(>64) ~ 1e-18)

typedef __attribute__((ext_vector_type(8))) short bf16x8;
typedef __attribute__((ext_vector_type(4))) float f32x4;

union FragU { uint u[4]; bf16x8 v; };

__device__ __forceinline__ uint bfr(float f) {          // f32 -> bf16 bits, RNE
    uint u = __float_as_uint(f);
    return (u + 0x7fffu + ((u >> 16) & 1u)) >> 16;
}
__device__ __forceinline__ uint pack_bf2(float a, float b) {
    return bfr(a) | (bfr(b) << 16);
}
__device__ __forceinline__ float bf2f(uint hi16) {      // bf16 bits (low 16) -> f32
    return __uint_as_float(hi16 << 16);
}

// ---------------------------------------------------------------------------
// Kernel 0: build MFMA weight-fragment table (blocks 0..40) AND zero cnt/stats
// (blocks 41..236). Frag mapping (verified rounds 2-6):
//   f in [0,16)  = W1^T (mt=f>>1,  ks=f&1)   [hid 16mt+r][k=32ks+8g+j]
//   f in [16,32) = W2^T (mt=(f-16)>>2, ks&3)
//   f in [32,40) = Wr^T (mt=(f-32)>>1, ks&1)
// ---------------------------------------------------------------------------
__global__ __launch_bounds__(256) void prep_kernel(
    const float* __restrict__ W1, const float* __restrict__ b1,
    const float* __restrict__ W2, const float* __restrict__ b2,
    const float* __restrict__ Wr, const float* __restrict__ br,
    uint* __restrict__ tbl, int* __restrict__ cnt, float* __restrict__ stats)
{
    const int f = blockIdx.x;
    const int tid = threadIdx.x;
    if (f < 40) {
        const int ln = tid >> 2, dd = tid & 3;
        const int g = ln >> 4, r = ln & 15;
        const int j0 = 2 * dd;
        float w0, w1v;
        if (f < 16) {
            const int mt = f >> 1, ks = f & 1;
            const int k = 32 * ks + 8 * g + j0, c = 16 * mt + r;
            w0 = W1[k * 128 + c];  w1v = W1[(k + 1) * 128 + c];
        } else if (f < 32) {
            const int mt = (f - 16) >> 2, ks = (f - 16) & 3;
            const int k = 32 * ks + 8 * g + j0, c = 16 * mt + r;
            w0 = W2[k * 64 + c];   w1v = W2[(k + 1) * 64 + c];
        } else {
            const int mt = (f - 32) >> 1, ks = (f - 32) & 1;
            const int k = 32 * ks + 8 * g + j0, c = 16 * mt + r;
            w0 = Wr[k * 64 + c];   w1v = Wr[(k + 1) * 64 + c];
        }
        tbl[f * 256 + tid] = pack_bf2(w0, w1v);
    } else if (f == 40) {
        if (tid < 128) tbl[10240 + tid] = __float_as_uint(b1[tid]);
        if (tid < 64) {
            tbl[10368 + tid] = __float_as_uint(b2[tid]);
            tbl[10432 + tid] = __float_as_uint(br[tid]);
        }
    } else {
        const int idx = (f - 41) * 256 + tid;
        if (idx < NNODES) cnt[idx] = 0;
        if (f == 41 && tid < 128) stats[tid] = 0.f;
    }
}

// ---------------------------------------------------------------------------
// Kernel 1: fused message-MLP + root transform via MFMA (bf16 in, f32 acc).
// W1/W2 frags register-resident per wave. Messages stored SPLIT: channels
// 0-31 -> M_lo (3.2 MB), 32-63 -> M_hi (3.2 MB) — separate address ranges so
// each gather pass's random working set fits a 4 MiB per-XCD L2.
// ---------------------------------------------------------------------------
__global__ __launch_bounds__(256) void mlp_root_kernel(
    const float* __restrict__ x, const uint* __restrict__ tbl,
    uint* __restrict__ MuL, uint* __restrict__ MuH, float* __restrict__ R)
{
    __shared__ uint  sH[4 * 16 * 68];          // per-wave H tile, 272 B/node row
    __shared__ float sb[256];                  // b1[128] | b2[64] | br[64]

    const int tid = threadIdx.x;
    if (tid < 128) {
        sb[tid]       = __uint_as_float(tbl[10240 + tid]);
        sb[128 + tid] = __uint_as_float(tbl[10368 + tid]);
    }
    __syncthreads();
    const float* sb1 = sb;
    const float* sb2 = sb + 128;
    const float* sbr = sb + 192;

    const int lane = tid & 63;
    const int g = lane >> 4, r = lane & 15;
    uint* Hw = &sH[(tid >> 6) * 16 * 68];

#define LDTBL(f) (*(const bf16x8*)&tbl[((f) << 8) | (lane << 2)])

    bf16x8 wf[32];
#pragma unroll
    for (int f = 0; f < 32; ++f) wf[f] = LDTBL(f);

    const int gw  = blockIdx.x * 4 + (tid >> 6);
    const int nwv = gridDim.x * 4;

    for (int t = gw; t < NTILES; t += nwv) {
        const int node = t * 16 + r;
        bf16x8 xf[2];
#pragma unroll
        for (int ks = 0; ks < 2; ++ks) {
            const float4 f0 = *(const float4*)&x[node * 64 + 32 * ks + 8 * g];
            const float4 f1 = *(const float4*)&x[node * 64 + 32 * ks + 8 * g + 4];
            FragU fx;
            fx.u[0] = pack_bf2(f0.x, f0.y); fx.u[1] = pack_bf2(f0.z, f0.w);
            fx.u[2] = pack_bf2(f1.x, f1.y); fx.u[3] = pack_bf2(f1.z, f1.w);
            xf[ks] = fx.v;
        }
#pragma unroll
        for (int mt = 0; mt < 8; ++mt) {
            f32x4 a = {0.f, 0.f, 0.f, 0.f};
            a = __builtin_amdgcn_mfma_f32_16x16x32_bf16(wf[2 * mt], xf[0], a, 0, 0, 0);
            a = __builtin_amdgcn_mfma_f32_16x16x32_bf16(wf[2 * mt + 1], xf[1], a, 0, 0, 0);
            const int hc = 16 * mt + 4 * g;
            const float v0 = fmaxf(a[0] + sb1[hc + 0], 0.f);
            const float v1 = fmaxf(a[1] + sb1[hc + 1], 0.f);
            const float v2 = fmaxf(a[2] + sb1[hc + 2], 0.f);
            const float v3 = fmaxf(a[3] + sb1[hc + 3], 0.f);
            const int hd = r * 68 + 8 * mt + 2 * g;
            Hw[hd]     = pack_bf2(v0, v1);
            Hw[hd + 1] = pack_bf2(v2, v3);
        }
        bf16x8 hf[4];
#pragma unroll
        for (int ks = 0; ks < 4; ++ks)
            hf[ks] = *(const bf16x8*)&Hw[r * 68 + 16 * ks + 4 * g];
#pragma unroll
        for (int mt = 0; mt < 4; ++mt) {
            f32x4 a2 = {0.f, 0.f, 0.f, 0.f};
#pragma unroll
            for (int ks = 0; ks < 4; ++ks)
                a2 = __builtin_amdgcn_mfma_f32_16x16x32_bf16(wf[16 + 4 * mt + ks], hf[ks], a2, 0, 0, 0);
            f32x4 ar = {0.f, 0.f, 0.f, 0.f};
            ar = __builtin_amdgcn_mfma_f32_16x16x32_bf16(LDTBL(32 + 2 * mt), xf[0], ar, 0, 0, 0);
            ar = __builtin_amdgcn_mfma_f32_16x16x32_bf16(LDTBL(32 + 2 * mt + 1), xf[1], ar, 0, 0, 0);
            const int oc = 16 * mt + 4 * g;
            const float m0 = a2[0] + sb2[oc + 0], m1 = a2[1] + sb2[oc + 1];
            const float m2 = a2[2] + sb2[oc + 2], m3 = a2[3] + sb2[oc + 3];
            uint2 mp = make_uint2(pack_bf2(m0, m1), pack_bf2(m2, m3));
            uint* dst = (mt < 2) ? MuL : MuH;          // channel-half split
            *(uint2*)&dst[node * 16 + 8 * (mt & 1) + 2 * g] = mp;
            float4 rv = make_float4(ar[0] + sbr[oc + 0], ar[1] + sbr[oc + 1],
                                    ar[2] + sbr[oc + 2], ar[3] + sbr[oc + 3]);
            *(float4*)&R[node * 64 + oc] = rv;
        }
    }
#undef LDTBL
}

// ---------------------------------------------------------------------------
// Kernel 2: bucket fill (ushort src ids; N < 65536).
// ---------------------------------------------------------------------------
__global__ __launch_bounds__(256) void fill_kernel(
    const int* __restrict__ ei, int* __restrict__ cnt, ushort* __restrict__ bucketU)
{
    const int e = blockIdx.x * 256 + threadIdx.x;
    const int dst = ei[NEDGES + e];
    const int pos = atomicAdd(&cnt[dst], 1);
    if (pos < CAP) bucketU[dst * CAP + pos] = (ushort)ei[e];
}

// ---------------------------------------------------------------------------
// Kernel 3: gather, one CHANNEL-HALF per launch. Mh = 3.2 MB half-table
// (fits every XCD's 4 MiB L2 -> random reads become L2 hits after warm).
// Wave processes a node PAIR (nA, nA+1): message load = uint (2 bf16 ch),
// 16-lane groups cover the 64 B half-row; q=lane>>4 -> 4 msgs per round.
// Store/stats phase: lanes 0-31 own node A's 32 channels, lanes 32-63 node B.
// Masked lanes clamp shfl idx to 0 (valid line, value cndmask'd to 0) — no
// exec-mask ops, wave-uniform bounds everywhere.
// ---------------------------------------------------------------------------
__global__ __launch_bounds__(256) void gather_half_kernel(
    const int* __restrict__ cnt, const ushort* __restrict__ bucketU,
    const uint* __restrict__ Mh, const float* __restrict__ pw,
    float* __restrict__ h, float* __restrict__ stats, const int choff)
{
    __shared__ float ls[64];                   // sum[32] | sumsq[32] (this half)
    const int tid = threadIdx.x;
    if (tid < 64) ls[tid] = 0.f;
    __syncthreads();

    const int lane = tid & 63;
    const int q    = lane >> 4;                // message slot within group of 4
    const int u    = lane & 15;                // uint index within 64 B half-row
    const int isB  = lane >> 5;                // store phase: 0 -> node A, 1 -> node B
    const int ch   = lane & 31;                // channel within half
    const float p  = pw[0];
    const int gw   = (blockIdx.x * 256 + tid) >> 6;
    const int nwv  = (gridDim.x * 256) >> 6;
    float sum = 0.f, sumsq = 0.f;

    int pi = gw;
    int cA = 0, svA = 0, cB = 0, svB = 0; float hv = 0.f;
    if (2 * pi < NNODES) {
        const int nA = 2 * pi;
        cA = cnt[nA]; cB = cnt[nA + 1];
        svA = (int)bucketU[nA * 64 + lane];
        svB = (int)bucketU[(nA + 1) * 64 + lane];
        hv  = h[(nA + isB) * 64 + choff + ch];
    }

    while (2 * pi < NNODES) {
        const int nA = 2 * pi;
        const int ca = cA > CAP ? CAP : cA;
        const int cb = cB > CAP ? CAP : cB;

        // bursts: up to 16 independent uint loads in flight
        uint mvA[8], mvB[8];
#pragma unroll
        for (int j = 0; j < 4; ++j) {
            const int ia = 4 * j + q;
            mvA[j] = Mh[(uint)__shfl(svA, ia < ca ? ia : 0) * 16u + u];
        }
        if (ca > 16) {
#pragma unroll
            for (int j = 4; j < 8; ++j) {
                const int ia = 4 * j + q;
                mvA[j] = Mh[(uint)__shfl(svA, ia < ca ? ia : 0) * 16u + u];
            }
        }
#pragma unroll
        for (int j = 0; j < 4; ++j) {
            const int ib = 4 * j + q;
            mvB[j] = Mh[(uint)__shfl(svB, ib < cb ? ib : 0) * 16u + u];
        }
        if (cb > 16) {
#pragma unroll
            for (int j = 4; j < 8; ++j) {
                const int ib = 4 * j + q;
                mvB[j] = Mh[(uint)__shfl(svB, ib < cb ? ib : 0) * 16u + u];
            }
        }

        // prefetch next pair while loads are in flight
        const int pin = pi + nwv;
        int c2 = 0, s2 = 0, c3 = 0, s3 = 0; float h2 = 0.f;
        if (2 * pin < NNODES) {
            const int n2 = 2 * pin;
            c2 = cnt[n2]; c3 = cnt[n2 + 1];
            s2 = (int)bucketU[n2 * 64 + lane];
            s3 = (int)bucketU[(n2 + 1) * 64 + lane];
            h2 = h[(n2 + isB) * 64 + choff + ch];
        }

        // unpack A
        float a0A, a1A;
        {
            float a0 = 0.f, a1 = 0.f, x0 = 0.f, x1 = 0.f;
#pragma unroll
            for (int j = 0; j < 4; ++j) {
                const uint v = ((4 * j + q) < ca) ? mvA[j] : 0u;
                if (j & 1) { x0 += bf2f(v & 0xffffu); x1 += bf2f(v >> 16); }
                else       { a0 += bf2f(v & 0xffffu); a1 += bf2f(v >> 16); }
            }
            if (ca > 16) {
#pragma unroll
                for (int j = 4; j < 8; ++j) {
                    const uint v = ((4 * j + q) < ca) ? mvA[j] : 0u;
                    if (j & 1) { x0 += bf2f(v & 0xffffu); x1 += bf2f(v >> 16); }
                    else       { a0 += bf2f(v & 0xffffu); a1 += bf2f(v >> 16); }
                }
                if (ca > 32) {                     // rare tail, quarter-partitioned
                    for (int i = 32; i < ca; i += 4) {
                        const int idx = i + q;
                        const uint mv = Mh[(uint)__shfl(svA, idx < ca ? idx : 0) * 16u + u];
                        const uint v = (idx < ca) ? mv : 0u;
                        a0 += bf2f(v & 0xffffu); a1 += bf2f(v >> 16);
                    }
                }
            }
            a0A = a0 + x0; a1A = a1 + x1;
        }
        // unpack B
        float a0B, a1B;
        {
            float a0 = 0.f, a1 = 0.f, x0 = 0.f, x1 = 0.f;
#pragma unroll
            for (int j = 0; j < 4; ++j) {
                const uint v = ((4 * j + q) < cb) ? mvB[j] : 0u;
                if (j & 1) { x0 += bf2f(v & 0xffffu); x1 += bf2f(v >> 16); }
                else       { a0 += bf2f(v & 0xffffu); a1 += bf2f(v >> 16); }
            }
            if (cb > 16) {
#pragma unroll
                for (int j = 4; j < 8; ++j) {
                    const uint v = ((4 * j + q) < cb) ? mvB[j] : 0u;
                    if (j & 1) { x0 += bf2f(v & 0xffffu); x1 += bf2f(v >> 16); }
                    else       { a0 += bf2f(v & 0xffffu); a1 += bf2f(v >> 16); }
                }
                if (cb > 32) {
                    for (int i = 32; i < cb; i += 4) {
                        const int idx = i + q;
                        const uint mv = Mh[(uint)__shfl(svB, idx < cb ? idx : 0) * 16u + u];
                        const uint v = (idx < cb) ? mv : 0u;
                        a0 += bf2f(v & 0xffffu); a1 += bf2f(v >> 16);
                    }
                }
            }
            a0B = a0 + x0; a1B = a1 + x1;
        }

        // combine quarters (each lane ends with full sums for channels 2u, 2u+1)
        a0A += __shfl_xor(a0A, 16); a0A += __shfl_xor(a0A, 32);
        a1A += __shfl_xor(a1A, 16); a1A += __shfl_xor(a1A, 32);
        a0B += __shfl_xor(a0B, 16); a0B += __shfl_xor(a0B, 32);
        a1B += __shfl_xor(a1B, 16); a1B += __shfl_xor(a1B, 32);

        // redistribute: lane's channel ch lives in uint u=ch>>1 (parity ch&1);
        // A-half lanes read from lanes 0-15, B-half from lanes 32-47.
        const int srcl = (ch >> 1) + (isB << 5);
        const float sel0 = isB ? a0B : a0A;
        const float sel1 = isB ? a1B : a1A;
        const float t0 = __shfl(sel0, srcl);
        const float t1 = __shfl(sel1, srcl);
        float v = hv + ((ch & 1) ? t1 : t0);
        v = (v >= 0.f) ? v : p * v;
        h[(nA + isB) * 64 + choff + ch] = v;
        sum += v;
        sumsq = fmaf(v, v, sumsq);

        pi = pin; cA = c2; svA = s2; cB = c3; svB = s3; hv = h2;
    }
    atomicAdd(&ls[ch], sum);
    atomicAdd(&ls[32 + ch], sumsq);
    __syncthreads();
    if (tid < 32)       atomicAdd(&stats[choff + tid], ls[tid]);
    else if (tid < 64)  atomicAdd(&stats[64 + choff + (tid - 32)], ls[tid]);
}

// ---------------------------------------------------------------------------
// Kernel 4: BatchNorm (training-mode batch stats, biased var), float4.
// 800000 float4s = 3125 blocks x 256 threads exactly.
// ---------------------------------------------------------------------------
__global__ __launch_bounds__(256) void bn_kernel(
    float4* __restrict__ h, const float* __restrict__ stats,
    const float* __restrict__ gamma, const float* __restrict__ beta)
{
    const int i  = blockIdx.x * 256 + threadIdx.x;
    const int c0 = (i & 15) * 4;
    const float inv = 1.0f / (float)NNODES;
    const float4 s1 = *(const float4*)&stats[c0];
    const float4 s2 = *(const float4*)&stats[64 + c0];
    const float4 gm = *(const float4*)&gamma[c0];
    const float4 bt = *(const float4*)&beta[c0];
    float4 v = h[i];
    float mu, var;
    mu = s1.x * inv; var = s2.x * inv - mu * mu; v.x = (v.x - mu) * (gm.x * rsqrtf(var + 1e-5f)) + bt.x;
    mu = s1.y * inv; var = s2.y * inv - mu * mu; v.y = (v.y - mu) * (gm.y * rsqrtf(var + 1e-5f)) + bt.y;
    mu = s1.z * inv; var = s2.z * inv - mu * mu; v.z = (v.z - mu) * (gm.z * rsqrtf(var + 1e-5f)) + bt.z;
    mu = s1.w * inv; var = s2.w * inv - mu * mu; v.w = (v.w - mu) * (gm.w * rsqrtf(var + 1e-5f)) + bt.w;
    h[i] = v;
}

extern "C" void kernel_launch(void* const* d_in, const int* in_sizes, int n_in,
                              void* d_out, int out_size, void* d_ws, size_t ws_size,
                              hipStream_t stream) {
    const float* x     = (const float*)d_in[0];
    const int*   ei    = (const int*)d_in[1];
    const float* W1    = (const float*)d_in[2];
    const float* b1    = (const float*)d_in[3];
    const float* W2    = (const float*)d_in[4];
    const float* b2    = (const float*)d_in[5];
    const float* Wr    = (const float*)d_in[6];
    const float* br    = (const float*)d_in[7];
    const float* pw    = (const float*)d_in[8];
    const float* gamma = (const float*)d_in[9];
    const float* beta  = (const float*)d_in[10];

    float* out = (float*)d_out;

    // workspace layout
    char* ws = (char*)d_ws;
    uint*   M_lo   = (uint*)ws;                                    //  3.2 MB (ch 0-31)
    uint*   M_hi   = (uint*)(ws + 3200000);                        //  3.2 MB (ch 32-63)
    ushort* bucketU= (ushort*)(ws + 6400000);                      //  6.4 MB
    int*    cnt    = (int*)(ws + 12800000);                        //  200 KB
    float*  stats  = (float*)(ws + 13000000);                      //  512 B
    uint*   tbl    = (uint*)(ws + 13000512);                       //  41 KB

    prep_kernel<<<237, 256, 0, stream>>>(W1, b1, W2, b2, Wr, br, tbl, cnt, stats);
    fill_kernel<<<NEDGES / 256, 256, 0, stream>>>(ei, cnt, bucketU);
    mlp_root_kernel<<<256, 256, 0, stream>>>(x, tbl, M_lo, M_hi, out);
    gather_half_kernel<<<2048, 256, 0, stream>>>(cnt, bucketU, M_lo, pw, out, stats, 0);
    gather_half_kernel<<<2048, 256, 0, stream>>>(cnt, bucketU, M_hi, pw, out, stats, 32);
    bn_kernel<<<3125, 256, 0, stream>>>((float4*)out, stats, gamma, beta);
}

// Round 8
// 207.833 us; speedup vs baseline: 1.0285x; 1.0285x over previous
//
#include <hip/hip_runtime.h>

#define NNODES 50000
#define NEDGES 800000
#define NTILES 3125      // 50000 / 16
#define CAP    64        // bucket capacity per dst node (Poisson(16); P(>64) ~ 1e-18)
#define NFILLB 625       // fill blocks: 625*256*5 = 800000 exactly
#define NMLPB  256       // mlp tile blocks

typedef __attribute__((ext_vector_type(8))) short bf16x8;
typedef __attribute__((ext_vector_type(4))) float f32x4;

union FragU { uint u[4]; bf16x8 v; };

__device__ __forceinline__ uint bfr(float f) {          // f32 -> bf16 bits, RNE
    uint u = __float_as_uint(f);
    return (u + 0x7fffu + ((u >> 16) & 1u)) >> 16;
}
__device__ __forceinline__ uint pack_bf2(float a, float b) {
    return bfr(a) | (bfr(b) << 16);
}
__device__ __forceinline__ float bf2f(uint hi16) {      // bf16 bits (low 16) -> f32
    return __uint_as_float(hi16 << 16);
}

// ---------------------------------------------------------------------------
// Kernel 0: build MFMA weight-fragment table (blocks 0..40) AND zero cnt/stats
// (blocks 41..236). Frag mapping (verified rounds 2-7):
//   f in [0,16)  = W1^T (mt=f>>1,  ks=f&1)   [hid 16mt+r][k=32ks+8g+j]
//   f in [16,32) = W2^T (mt=(f-16)>>2, ks&3)
//   f in [32,40) = Wr^T (mt=(f-32)>>1, ks&1)
// ---------------------------------------------------------------------------
__global__ __launch_bounds__(256) void prep_kernel(
    const float* __restrict__ W1, const float* __restrict__ b1,
    const float* __restrict__ W2, const float* __restrict__ b2,
    const float* __restrict__ Wr, const float* __restrict__ br,
    uint* __restrict__ tbl, int* __restrict__ cnt, float* __restrict__ stats)
{
    const int f = blockIdx.x;
    const int tid = threadIdx.x;
    if (f < 40) {
        const int ln = tid >> 2, dd = tid & 3;
        const int g = ln >> 4, r = ln & 15;
        const int j0 = 2 * dd;
        float w0, w1v;
        if (f < 16) {
            const int mt = f >> 1, ks = f & 1;
            const int k = 32 * ks + 8 * g + j0, c = 16 * mt + r;
            w0 = W1[k * 128 + c];  w1v = W1[(k + 1) * 128 + c];
        } else if (f < 32) {
            const int mt = (f - 16) >> 2, ks = (f - 16) & 3;
            const int k = 32 * ks + 8 * g + j0, c = 16 * mt + r;
            w0 = W2[k * 64 + c];   w1v = W2[(k + 1) * 64 + c];
        } else {
            const int mt = (f - 32) >> 1, ks = (f - 32) & 1;
            const int k = 32 * ks + 8 * g + j0, c = 16 * mt + r;
            w0 = Wr[k * 64 + c];   w1v = Wr[(k + 1) * 64 + c];
        }
        tbl[f * 256 + tid] = pack_bf2(w0, w1v);
    } else if (f == 40) {
        if (tid < 128) tbl[10240 + tid] = __float_as_uint(b1[tid]);
        if (tid < 64) {
            tbl[10368 + tid] = __float_as_uint(b2[tid]);
            tbl[10432 + tid] = __float_as_uint(br[tid]);
        }
    } else {
        const int idx = (f - 41) * 256 + tid;
        if (idx < NNODES) cnt[idx] = 0;
        if (f == 41 && tid < 128) stats[tid] = 0.f;
    }
}

// ---------------------------------------------------------------------------
// Kernel 1: FUSED bucket-fill + message-MLP/root-MFMA.
// Blocks 0..624: fill — each thread owns exactly 5 edges (stride 160000),
//   issuing 5 INDEPENDENT load->atomicAdd->store chains (vs 1 in round 7) so
//   the coherence-point atomic latency pipelines. Blocks 625..880: the
//   round-6 MFMA tile path (W1/W2 frags register-resident). Atomic-stalled
//   fill waves and MFMA waves co-schedule on the same CUs -> mlp time hides
//   under fill latency.
// ---------------------------------------------------------------------------
__global__ __launch_bounds__(256) void fused_fill_mlp_kernel(
    const int* __restrict__ ei, int* __restrict__ cnt, ushort* __restrict__ bucketU,
    const float* __restrict__ x, const uint* __restrict__ tbl,
    ushort* __restrict__ M16, float* __restrict__ R)
{
    __shared__ uint  sH[4 * 16 * 68];          // tile path: per-wave H, 272 B/row
    __shared__ float sb[256];                  // tile path: b1[128]|b2[64]|br[64]

    const int tid = threadIdx.x;

    if (blockIdx.x < NFILLB) {
        // ---- fill path: 5 edges/thread, batched phases for ILP ----
        const int t0 = blockIdx.x * 256 + tid;
        int dst[5], src[5];
#pragma unroll
        for (int j = 0; j < 5; ++j) {
            dst[j] = ei[NEDGES + t0 + j * 160000];
            src[j] = ei[t0 + j * 160000];
        }
        int pos[5];
#pragma unroll
        for (int j = 0; j < 5; ++j) pos[j] = atomicAdd(&cnt[dst[j]], 1);
#pragma unroll
        for (int j = 0; j < 5; ++j)
            if (pos[j] < CAP) bucketU[dst[j] * CAP + pos[j]] = (ushort)src[j];
        return;
    }

    // ---- tile path (round-6 mlp_root verbatim, grid = NMLPB blocks) ----
    if (tid < 128) {
        sb[tid]       = __uint_as_float(tbl[10240 + tid]);
        sb[128 + tid] = __uint_as_float(tbl[10368 + tid]);
    }
    __syncthreads();
    const float* sb1 = sb;
    const float* sb2 = sb + 128;
    const float* sbr = sb + 192;

    const int lane = tid & 63;
    const int g = lane >> 4, r = lane & 15;
    uint* Hw = &sH[(tid >> 6) * 16 * 68];
    uint* Mu = (uint*)M16;

#define LDTBL(f) (*(const bf16x8*)&tbl[((f) << 8) | (lane << 2)])

    bf16x8 wf[32];
#pragma unroll
    for (int f = 0; f < 32; ++f) wf[f] = LDTBL(f);

    const int gw  = (blockIdx.x - NFILLB) * 4 + (tid >> 6);
    const int nwv = NMLPB * 4;

    for (int t = gw; t < NTILES; t += nwv) {
        const int node = t * 16 + r;
        bf16x8 xf[2];
#pragma unroll
        for (int ks = 0; ks < 2; ++ks) {
            const float4 f0 = *(const float4*)&x[node * 64 + 32 * ks + 8 * g];
            const float4 f1 = *(const float4*)&x[node * 64 + 32 * ks + 8 * g + 4];
            FragU fx;
            fx.u[0] = pack_bf2(f0.x, f0.y); fx.u[1] = pack_bf2(f0.z, f0.w);
            fx.u[2] = pack_bf2(f1.x, f1.y); fx.u[3] = pack_bf2(f1.z, f1.w);
            xf[ks] = fx.v;
        }
#pragma unroll
        for (int mt = 0; mt < 8; ++mt) {
            f32x4 a = {0.f, 0.f, 0.f, 0.f};
            a = __builtin_amdgcn_mfma_f32_16x16x32_bf16(wf[2 * mt], xf[0], a, 0, 0, 0);
            a = __builtin_amdgcn_mfma_f32_16x16x32_bf16(wf[2 * mt + 1], xf[1], a, 0, 0, 0);
            const int hc = 16 * mt + 4 * g;
            const float v0 = fmaxf(a[0] + sb1[hc + 0], 0.f);
            const float v1 = fmaxf(a[1] + sb1[hc + 1], 0.f);
            const float v2 = fmaxf(a[2] + sb1[hc + 2], 0.f);
            const float v3 = fmaxf(a[3] + sb1[hc + 3], 0.f);
            const int hd = r * 68 + 8 * mt + 2 * g;
            Hw[hd]     = pack_bf2(v0, v1);
            Hw[hd + 1] = pack_bf2(v2, v3);
        }
        bf16x8 hf[4];
#pragma unroll
        for (int ks = 0; ks < 4; ++ks)
            hf[ks] = *(const bf16x8*)&Hw[r * 68 + 16 * ks + 4 * g];
#pragma unroll
        for (int mt = 0; mt < 4; ++mt) {
            f32x4 a2 = {0.f, 0.f, 0.f, 0.f};
#pragma unroll
            for (int ks = 0; ks < 4; ++ks)
                a2 = __builtin_amdgcn_mfma_f32_16x16x32_bf16(wf[16 + 4 * mt + ks], hf[ks], a2, 0, 0, 0);
            f32x4 ar = {0.f, 0.f, 0.f, 0.f};
            ar = __builtin_amdgcn_mfma_f32_16x16x32_bf16(LDTBL(32 + 2 * mt), xf[0], ar, 0, 0, 0);
            ar = __builtin_amdgcn_mfma_f32_16x16x32_bf16(LDTBL(32 + 2 * mt + 1), xf[1], ar, 0, 0, 0);
            const int oc = 16 * mt + 4 * g;
            const float m0 = a2[0] + sb2[oc + 0], m1 = a2[1] + sb2[oc + 1];
            const float m2 = a2[2] + sb2[oc + 2], m3 = a2[3] + sb2[oc + 3];
            uint2 mp = make_uint2(pack_bf2(m0, m1), pack_bf2(m2, m3));
            *(uint2*)&Mu[node * 32 + 8 * mt + 2 * g] = mp;
            float4 rv = make_float4(ar[0] + sbr[oc + 0], ar[1] + sbr[oc + 1],
                                    ar[2] + sbr[oc + 2], ar[3] + sbr[oc + 3]);
            *(float4*)&R[node * 64 + oc] = rv;
        }
    }
#undef LDTBL
}

// ---------------------------------------------------------------------------
// Kernel 3 helpers: one node's burst / unpack / combine (round-5/6-verified)
// ---------------------------------------------------------------------------
__device__ __forceinline__ void burst_load(const uint2* __restrict__ M8, int sv,
                                           int c, int q, int u, uint2 mv[8])
{
#pragma unroll
    for (int j = 0; j < 4; ++j) {
        const int idx = 4 * j + q;
        const int s = __shfl(sv, (idx < c) ? idx : 0);
        mv[j] = M8[s * 16 + u];
    }
    if (c > 16) {                              // wave-uniform
#pragma unroll
        for (int j = 4; j < 8; ++j) {
            const int idx = 4 * j + q;
            const int s = __shfl(sv, (idx < c) ? idx : 0);
            mv[j] = M8[s * 16 + u];
        }
    }
}

__device__ __forceinline__ void unpack_acc(const uint2 mv[8], int c, int q, int u,
                                           const uint2* __restrict__ M8, int sv,
                                           float& A0, float& A1, float& A2, float& A3)
{
    float a0 = 0.f, a1 = 0.f, a2 = 0.f, a3 = 0.f;
    float b0 = 0.f, b1 = 0.f, b2 = 0.f, b3 = 0.f;
#pragma unroll
    for (int j = 0; j < 4; ++j) {
        const bool ok = (4 * j + q) < c;
        const uint lo = ok ? mv[j].x : 0u;
        const uint hi = ok ? mv[j].y : 0u;
        if (j & 1) { b0 += bf2f(lo & 0xffffu); b1 += bf2f(lo >> 16);
                     b2 += bf2f(hi & 0xffffu); b3 += bf2f(hi >> 16); }
        else       { a0 += bf2f(lo & 0xffffu); a1 += bf2f(lo >> 16);
                     a2 += bf2f(hi & 0xffffu); a3 += bf2f(hi >> 16); }
    }
    if (c > 16) {                              // wave-uniform
#pragma unroll
        for (int j = 4; j < 8; ++j) {
            const bool ok = (4 * j + q) < c;
            const uint lo = ok ? mv[j].x : 0u;
            const uint hi = ok ? mv[j].y : 0u;
            if (j & 1) { b0 += bf2f(lo & 0xffffu); b1 += bf2f(lo >> 16);
                         b2 += bf2f(hi & 0xffffu); b3 += bf2f(hi >> 16); }
            else       { a0 += bf2f(lo & 0xffffu); a1 += bf2f(lo >> 16);
                         a2 += bf2f(hi & 0xffffu); a3 += bf2f(hi >> 16); }
        }
        if (c > 32) {                          // rare tail, quarter-partitioned
            for (int i = 32; i < c; i += 4) {
                const int idx = i + q;
                const int s = __shfl(sv, (idx < c) ? idx : 0);
                const uint2 m = M8[s * 16 + u];
                const bool ok = idx < c;
                const uint lo = ok ? m.x : 0u;
                const uint hi = ok ? m.y : 0u;
                a0 += bf2f(lo & 0xffffu); a1 += bf2f(lo >> 16);
                a2 += bf2f(hi & 0xffffu); a3 += bf2f(hi >> 16);
            }
        }
    }
    A0 = a0 + b0; A1 = a1 + b1; A2 = a2 + b2; A3 = a3 + b3;
}

__device__ __forceinline__ void combine_store(float a0, float a1, float a2, float a3,
                                              float hv, float p, int lane,
                                              float* __restrict__ hrow,
                                              float& sum, float& sumsq)
{
    a0 += __shfl_xor(a0, 16); a0 += __shfl_xor(a0, 32);
    a1 += __shfl_xor(a1, 16); a1 += __shfl_xor(a1, 32);
    a2 += __shfl_xor(a2, 16); a2 += __shfl_xor(a2, 32);
    a3 += __shfl_xor(a3, 16); a3 += __shfl_xor(a3, 32);
    const int srcl = lane >> 2;
    const float t0 = __shfl(a0, srcl), t1 = __shfl(a1, srcl);
    const float t2 = __shfl(a2, srcl), t3 = __shfl(a3, srcl);
    const float e01 = (lane & 1) ? t1 : t0;
    const float e23 = (lane & 1) ? t3 : t2;
    float v = hv + ((lane & 2) ? e23 : e01);
    v = (v >= 0.f) ? v : p * v;
    hrow[lane] = v;
    sum += v;
    sumsq = fmaf(v, v, sumsq);
}

// ---------------------------------------------------------------------------
// Kernel 3: gather v4 (round-6 verbatim) — pair-unrolled, up to 16 loads in
// flight, second burst half skipped wave-uniformly when c<=16.
// ---------------------------------------------------------------------------
__global__ __launch_bounds__(256) void gather_prelu_stats_kernel(
    const int* __restrict__ cnt, const ushort* __restrict__ bucketU,
    const uint2* __restrict__ M8, const float* __restrict__ pw,
    float* __restrict__ h, float* __restrict__ stats)
{
    __shared__ float ls[128];
    const int tid = threadIdx.x;
    if (tid < 128) ls[tid] = 0.f;
    __syncthreads();

    const int lane = tid & 63;
    const int q    = lane >> 4;
    const int u    = lane & 15;
    const int gw   = (blockIdx.x * 256 + tid) >> 6;
    const int nwv  = (gridDim.x * 256) >> 6;
    const float p  = pw[0];
    float sum = 0.f, sumsq = 0.f;

    int nA = gw, nB = gw + nwv;
    int cA = 0, svA = 0; float hA = 0.f;
    if (nA < NNODES) { cA = cnt[nA]; svA = (int)bucketU[nA * 64 + lane]; hA = h[nA * 64 + lane]; }
    int cB = 0, svB = 0; float hB = 0.f;
    if (nB < NNODES) { cB = cnt[nB]; svB = (int)bucketU[nB * 64 + lane]; hB = h[nB * 64 + lane]; }

    while (nA < NNODES) {
        const int  ca   = cA > CAP ? CAP : cA;
        const int  cb   = cB > CAP ? CAP : cB;
        const bool hasB = nB < NNODES;

        uint2 mvA[8], mvB[8];
        burst_load(M8, svA, ca, q, u, mvA);
        if (hasB) burst_load(M8, svB, cb, q, u, mvB);

        const int n2 = nA + 2 * nwv, n3 = nB + 2 * nwv;
        int c2 = 0, s2 = 0; float h2 = 0.f;
        int c3 = 0, s3 = 0; float h3 = 0.f;
        if (n2 < NNODES) { c2 = cnt[n2]; s2 = (int)bucketU[n2 * 64 + lane]; h2 = h[n2 * 64 + lane]; }
        if (n3 < NNODES) { c3 = cnt[n3]; s3 = (int)bucketU[n3 * 64 + lane]; h3 = h[n3 * 64 + lane]; }

        float A0, A1, A2, A3;
        unpack_acc(mvA, ca, q, u, M8, svA, A0, A1, A2, A3);
        combine_store(A0, A1, A2, A3, hA, p, lane, &h[nA * 64], sum, sumsq);

        if (hasB) {
            float B0, B1, B2, B3;
            unpack_acc(mvB, cb, q, u, M8, svB, B0, B1, B2, B3);
            combine_store(B0, B1, B2, B3, hB, p, lane, &h[nB * 64], sum, sumsq);
        }

        nA = n2; nB = n3;
        cA = c2; svA = s2; hA = h2;
        cB = c3; svB = s3; hB = h3;
    }
    atomicAdd(&ls[lane], sum);
    atomicAdd(&ls[64 + lane], sumsq);
    __syncthreads();
    if (tid < 128) atomicAdd(&stats[tid], ls[tid]);
}

// ---------------------------------------------------------------------------
// Kernel 4: BatchNorm (training-mode batch stats, biased var), float4.
// 800000 float4s = 3125 blocks x 256 threads exactly.
// ---------------------------------------------------------------------------
__global__ __launch_bounds__(256) void bn_kernel(
    float4* __restrict__ h, const float* __restrict__ stats,
    const float* __restrict__ gamma, const float* __restrict__ beta)
{
    const int i  = blockIdx.x * 256 + threadIdx.x;
    const int c0 = (i & 15) * 4;
    const float inv = 1.0f / (float)NNODES;
    const float4 s1 = *(const float4*)&stats[c0];
    const float4 s2 = *(const float4*)&stats[64 + c0];
    const float4 gm = *(const float4*)&gamma[c0];
    const float4 bt = *(const float4*)&beta[c0];
    float4 v = h[i];
    float mu, var;
    mu = s1.x * inv; var = s2.x * inv - mu * mu; v.x = (v.x - mu) * (gm.x * rsqrtf(var + 1e-5f)) + bt.x;
    mu = s1.y * inv; var = s2.y * inv - mu * mu; v.y = (v.y - mu) * (gm.y * rsqrtf(var + 1e-5f)) + bt.y;
    mu = s1.z * inv; var = s2.z * inv - mu * mu; v.z = (v.z - mu) * (gm.z * rsqrtf(var + 1e-5f)) + bt.z;
    mu = s1.w * inv; var = s2.w * inv - mu * mu; v.w = (v.w - mu) * (gm.w * rsqrtf(var + 1e-5f)) + bt.w;
    h[i] = v;
}

extern "C" void kernel_launch(void* const* d_in, const int* in_sizes, int n_in,
                              void* d_out, int out_size, void* d_ws, size_t ws_size,
                              hipStream_t stream) {
    const float* x     = (const float*)d_in[0];
    const int*   ei    = (const int*)d_in[1];
    const float* W1    = (const float*)d_in[2];
    const float* b1    = (const float*)d_in[3];
    const float* W2    = (const float*)d_in[4];
    const float* b2    = (const float*)d_in[5];
    const float* Wr    = (const float*)d_in[6];
    const float* br    = (const float*)d_in[7];
    const float* pw    = (const float*)d_in[8];
    const float* gamma = (const float*)d_in[9];
    const float* beta  = (const float*)d_in[10];

    float* out = (float*)d_out;

    // workspace layout
    char* ws = (char*)d_ws;
    ushort* M16    = (ushort*)ws;                                  //  6.4 MB
    ushort* bucketU= (ushort*)(ws + 6400000);                      //  6.4 MB
    int*    cnt    = (int*)(ws + 12800000);                        //  200 KB
    float*  stats  = (float*)(ws + 13000000);                      //  512 B
    uint*   tbl    = (uint*)(ws + 13000512);                       //  41 KB

    prep_kernel<<<237, 256, 0, stream>>>(W1, b1, W2, b2, Wr, br, tbl, cnt, stats);
    fused_fill_mlp_kernel<<<NFILLB + NMLPB, 256, 0, stream>>>(ei, cnt, bucketU, x, tbl, M16, out);
    gather_prelu_stats_kernel<<<2048, 256, 0, stream>>>(cnt, bucketU, (const uint2*)M16, pw, out, stats);
    bn_kernel<<<3125, 256, 0, stream>>>((float4*)out, stats, gamma, beta);
}

// Round 10
// 203.934 us; speedup vs baseline: 1.0482x; 1.0191x over previous
//
#include <hip/hip_runtime.h>

#define NNODES 50000
#define NEDGES 800000
#define NTILES 3125      // 50000 / 16
#define CAP    64        // bucket capacity per dst node (Poisson(16); P(>64) ~ 1e-18)
#define FILLB  782       // fill blocks: 782*256 threads * 4 edges >= 800000 (masked)

typedef __attribute__((ext_vector_type(8))) short bf16x8;
typedef __attribute__((ext_vector_type(4))) float f32x4;

union FragU { uint u[4]; bf16x8 v; };

__device__ __forceinline__ uint bfr(float f) {          // f32 -> bf16 bits, RNE
    uint u = __float_as_uint(f);
    return (u + 0x7fffu + ((u >> 16) & 1u)) >> 16;
}
__device__ __forceinline__ uint pack_bf2(float a, float b) {
    return bfr(a) | (bfr(b) << 16);
}
__device__ __forceinline__ float bf2f(uint hi16) {      // bf16 bits (low 16) -> f32
    return __uint_as_float(hi16 << 16);
}

// ---------------------------------------------------------------------------
// Kernel 0: build MFMA weight-fragment table (blocks 0..40) AND zero cnt/stats
// (blocks 41..236). Frag mapping (verified rounds 2-8):
//   f in [0,16)  = W1^T (mt=f>>1,  ks=f&1)   [hid 16mt+r][k=32ks+8g+j]
//   f in [16,32) = W2^T (mt=(f-16)>>2, ks&3)
//   f in [32,40) = Wr^T (mt=(f-32)>>1, ks&1)
// ---------------------------------------------------------------------------
__global__ __launch_bounds__(256) void prep_kernel(
    const float* __restrict__ W1, const float* __restrict__ b1,
    const float* __restrict__ W2, const float* __restrict__ b2,
    const float* __restrict__ Wr, const float* __restrict__ br,
    uint* __restrict__ tbl, int* __restrict__ cnt, float* __restrict__ stats)
{
    const int f = blockIdx.x;
    const int tid = threadIdx.x;
    if (f < 40) {
        const int ln = tid >> 2, dd = tid & 3;
        const int g = ln >> 4, r = ln & 15;
        const int j0 = 2 * dd;
        float w0, w1v;
        if (f < 16) {
            const int mt = f >> 1, ks = f & 1;
            const int k = 32 * ks + 8 * g + j0, c = 16 * mt + r;
            w0 = W1[k * 128 + c];  w1v = W1[(k + 1) * 128 + c];
        } else if (f < 32) {
            const int mt = (f - 16) >> 2, ks = (f - 16) & 3;
            const int k = 32 * ks + 8 * g + j0, c = 16 * mt + r;
            w0 = W2[k * 64 + c];   w1v = W2[(k + 1) * 64 + c];
        } else {
            const int mt = (f - 32) >> 1, ks = (f - 32) & 1;
            const int k = 32 * ks + 8 * g + j0, c = 16 * mt + r;
            w0 = Wr[k * 64 + c];   w1v = Wr[(k + 1) * 64 + c];
        }
        tbl[f * 256 + tid] = pack_bf2(w0, w1v);
    } else if (f == 40) {
        if (tid < 128) tbl[10240 + tid] = __float_as_uint(b1[tid]);
        if (tid < 64) {
            tbl[10368 + tid] = __float_as_uint(b2[tid]);
            tbl[10432 + tid] = __float_as_uint(br[tid]);
        }
    } else {
        const int idx = (f - 41) * 256 + tid;
        if (idx < NNODES) cnt[idx] = 0;
        if (f == 41 && tid < 128) stats[tid] = 0.f;
    }
}

// ---------------------------------------------------------------------------
// Kernel 1: bucket fill v2 — 4-edge batched ILP at HIGH occupancy (low-VGPR,
// standalone). Phases: 8 index loads -> 4 independent atomicAdds in flight ->
// 4 scatter stores. ~48 outstanding wave-atomics/CU vs 32 in r7.
// ---------------------------------------------------------------------------
__global__ __launch_bounds__(256) void fill_kernel(
    const int* __restrict__ ei, int* __restrict__ cnt, ushort* __restrict__ bucketU)
{
    const int gtid = blockIdx.x * 256 + threadIdx.x;   // 200192 threads
    int dst[4], src[4];
    bool ok[4];
#pragma unroll
    for (int j = 0; j < 4; ++j) {
        const int e = gtid + j * 200192;
        ok[j] = e < NEDGES;
        const int ec = ok[j] ? e : 0;
        dst[j] = ei[NEDGES + ec];
        src[j] = ei[ec];
    }
    int pos[4];
#pragma unroll
    for (int j = 0; j < 4; ++j)
        pos[j] = ok[j] ? atomicAdd(&cnt[dst[j]], 1) : CAP;
#pragma unroll
    for (int j = 0; j < 4; ++j)
        if (pos[j] < CAP) bucketU[dst[j] * CAP + pos[j]] = (ushort)src[j];
}

// ---------------------------------------------------------------------------
// Kernel 2: message-MLP + root transform via MFMA (round-6 version verbatim).
// W1/W2 frags register-resident per wave; Wr frags from L1-hot tbl.
// ---------------------------------------------------------------------------
__global__ __launch_bounds__(256) void mlp_root_kernel(
    const float* __restrict__ x, const uint* __restrict__ tbl,
    ushort* __restrict__ M16, float* __restrict__ R)
{
    __shared__ uint  sH[4 * 16 * 68];          // per-wave H tile, 272 B/node row
    __shared__ float sb[256];                  // b1[128] | b2[64] | br[64]

    const int tid = threadIdx.x;
    if (tid < 128) {
        sb[tid]       = __uint_as_float(tbl[10240 + tid]);
        sb[128 + tid] = __uint_as_float(tbl[10368 + tid]);
    }
    __syncthreads();
    const float* sb1 = sb;
    const float* sb2 = sb + 128;
    const float* sbr = sb + 192;

    const int lane = tid & 63;
    const int g = lane >> 4, r = lane & 15;
    uint* Hw = &sH[(tid >> 6) * 16 * 68];
    uint* Mu = (uint*)M16;

#define LDTBL(f) (*(const bf16x8*)&tbl[((f) << 8) | (lane << 2)])

    bf16x8 wf[32];
#pragma unroll
    for (int f = 0; f < 32; ++f) wf[f] = LDTBL(f);

    const int gw  = blockIdx.x * 4 + (tid >> 6);
    const int nwv = gridDim.x * 4;

    for (int t = gw; t < NTILES; t += nwv) {
        const int node = t * 16 + r;
        bf16x8 xf[2];
#pragma unroll
        for (int ks = 0; ks < 2; ++ks) {
            const float4 f0 = *(const float4*)&x[node * 64 + 32 * ks + 8 * g];
            const float4 f1 = *(const float4*)&x[node * 64 + 32 * ks + 8 * g + 4];
            FragU fx;
            fx.u[0] = pack_bf2(f0.x, f0.y); fx.u[1] = pack_bf2(f0.z, f0.w);
            fx.u[2] = pack_bf2(f1.x, f1.y); fx.u[3] = pack_bf2(f1.z, f1.w);
            xf[ks] = fx.v;
        }
#pragma unroll
        for (int mt = 0; mt < 8; ++mt) {
            f32x4 a = {0.f, 0.f, 0.f, 0.f};
            a = __builtin_amdgcn_mfma_f32_16x16x32_bf16(wf[2 * mt], xf[0], a, 0, 0, 0);
            a = __builtin_amdgcn_mfma_f32_16x16x32_bf16(wf[2 * mt + 1], xf[1], a, 0, 0, 0);
            const int hc = 16 * mt + 4 * g;
            const float v0 = fmaxf(a[0] + sb1[hc + 0], 0.f);
            const float v1 = fmaxf(a[1] + sb1[hc + 1], 0.f);
            const float v2 = fmaxf(a[2] + sb1[hc + 2], 0.f);
            const float v3 = fmaxf(a[3] + sb1[hc + 3], 0.f);
            const int hd = r * 68 + 8 * mt + 2 * g;
            Hw[hd]     = pack_bf2(v0, v1);
            Hw[hd + 1] = pack_bf2(v2, v3);
        }
        bf16x8 hf[4];
#pragma unroll
        for (int ks = 0; ks < 4; ++ks)
            hf[ks] = *(const bf16x8*)&Hw[r * 68 + 16 * ks + 4 * g];
#pragma unroll
        for (int mt = 0; mt < 4; ++mt) {
            f32x4 a2 = {0.f, 0.f, 0.f, 0.f};
#pragma unroll
            for (int ks = 0; ks < 4; ++ks)
                a2 = __builtin_amdgcn_mfma_f32_16x16x32_bf16(wf[16 + 4 * mt + ks], hf[ks], a2, 0, 0, 0);
            f32x4 ar = {0.f, 0.f, 0.f, 0.f};
            ar = __builtin_amdgcn_mfma_f32_16x16x32_bf16(LDTBL(32 + 2 * mt), xf[0], ar, 0, 0, 0);
            ar = __builtin_amdgcn_mfma_f32_16x16x32_bf16(LDTBL(32 + 2 * mt + 1), xf[1], ar, 0, 0, 0);
            const int oc = 16 * mt + 4 * g;
            const float m0 = a2[0] + sb2[oc + 0], m1 = a2[1] + sb2[oc + 1];
            const float m2 = a2[2] + sb2[oc + 2], m3 = a2[3] + sb2[oc + 3];
            uint2 mp = make_uint2(pack_bf2(m0, m1), pack_bf2(m2, m3));
            *(uint2*)&Mu[node * 32 + 8 * mt + 2 * g] = mp;
            float4 rv = make_float4(ar[0] + sbr[oc + 0], ar[1] + sbr[oc + 1],
                                    ar[2] + sbr[oc + 2], ar[3] + sbr[oc + 3]);
            *(float4*)&R[node * 64 + oc] = rv;
        }
    }
#undef LDTBL
}

// ---------------------------------------------------------------------------
// Kernel 3 helpers (round-5/6-verified math)
// ---------------------------------------------------------------------------
__device__ __forceinline__ void burst_load(const uint2* __restrict__ M8, int sv,
                                           int c, int q, int u, uint2 mv[8])
{
#pragma unroll
    for (int j = 0; j < 4; ++j) {
        const int idx = 4 * j + q;
        const int s = __shfl(sv, (idx < c) ? idx : 0);
        mv[j] = M8[s * 16 + u];
    }
    if (c > 16) {                              // wave-uniform
#pragma unroll
        for (int j = 4; j < 8; ++j) {
            const int idx = 4 * j + q;
            const int s = __shfl(sv, (idx < c) ? idx : 0);
            mv[j] = M8[s * 16 + u];
        }
    }
}

__device__ __forceinline__ void unpack_acc(const uint2 mv[8], int c, int q, int u,
                                           const uint2* __restrict__ M8, int sv,
                                           float& A0, float& A1, float& A2, float& A3)
{
    float a0 = 0.f, a1 = 0.f, a2 = 0.f, a3 = 0.f;
    float b0 = 0.f, b1 = 0.f, b2 = 0.f, b3 = 0.f;
#pragma unroll
    for (int j = 0; j < 4; ++j) {
        const bool ok = (4 * j + q) < c;
        const uint lo = ok ? mv[j].x : 0u;
        const uint hi = ok ? mv[j].y : 0u;
        if (j & 1) { b0 += bf2f(lo & 0xffffu); b1 += bf2f(lo >> 16);
                     b2 += bf2f(hi & 0xffffu); b3 += bf2f(hi >> 16); }
        else       { a0 += bf2f(lo & 0xffffu); a1 += bf2f(lo >> 16);
                     a2 += bf2f(hi & 0xffffu); a3 += bf2f(hi >> 16); }
    }
    if (c > 16) {                              // wave-uniform
#pragma unroll
        for (int j = 4; j < 8; ++j) {
            const bool ok = (4 * j + q) < c;
            const uint lo = ok ? mv[j].x : 0u;
            const uint hi = ok ? mv[j].y : 0u;
            if (j & 1) { b0 += bf2f(lo & 0xffffu); b1 += bf2f(lo >> 16);
                         b2 += bf2f(hi & 0xffffu); b3 += bf2f(hi >> 16); }
            else       { a0 += bf2f(lo & 0xffffu); a1 += bf2f(lo >> 16);
                         a2 += bf2f(hi & 0xffffu); a3 += bf2f(hi >> 16); }
        }
        if (c > 32) {                          // rare tail, quarter-partitioned
            for (int i = 32; i < c; i += 4) {
                const int idx = i + q;
                const int s = __shfl(sv, (idx < c) ? idx : 0);
                const uint2 m = M8[s * 16 + u];
                const bool ok = idx < c;
                const uint lo = ok ? m.x : 0u;
                const uint hi = ok ? m.y : 0u;
                a0 += bf2f(lo & 0xffffu); a1 += bf2f(lo >> 16);
                a2 += bf2f(hi & 0xffffu); a3 += bf2f(hi >> 16);
            }
        }
    }
    A0 = a0 + b0; A1 = a1 + b1; A2 = a2 + b2; A3 = a3 + b3;
}

__device__ __forceinline__ void combine_store(float a0, float a1, float a2, float a3,
                                              float hv, float p, int lane,
                                              float* __restrict__ hrow,
                                              float& sum, float& sumsq)
{
    a0 += __shfl_xor(a0, 16); a0 += __shfl_xor(a0, 32);
    a1 += __shfl_xor(a1, 16); a1 += __shfl_xor(a1, 32);
    a2 += __shfl_xor(a2, 16); a2 += __shfl_xor(a2, 32);
    a3 += __shfl_xor(a3, 16); a3 += __shfl_xor(a3, 32);
    const int srcl = lane >> 2;
    const float t0 = __shfl(a0, srcl), t1 = __shfl(a1, srcl);
    const float t2 = __shfl(a2, srcl), t3 = __shfl(a3, srcl);
    const float e01 = (lane & 1) ? t1 : t0;
    const float e23 = (lane & 1) ? t3 : t2;
    float v = hv + ((lane & 2) ? e23 : e01);
    v = (v >= 0.f) ? v : p * v;
    hrow[lane] = v;
    sum += v;
    sumsq = fmaf(v, v, sumsq);
}

// ---------------------------------------------------------------------------
// Kernel 3: gather v4 (round-6 verbatim).
// ---------------------------------------------------------------------------
__global__ __launch_bounds__(256) void gather_prelu_stats_kernel(
    const int* __restrict__ cnt, const ushort* __restrict__ bucketU,
    const uint2* __restrict__ M8, const float* __restrict__ pw,
    float* __restrict__ h, float* __restrict__ stats)
{
    __shared__ float ls[128];
    const int tid = threadIdx.x;
    if (tid < 128) ls[tid] = 0.f;
    __syncthreads();

    const int lane = tid & 63;
    const int q    = lane >> 4;
    const int u    = lane & 15;
    const int gw   = (blockIdx.x * 256 + tid) >> 6;
    const int nwv  = (gridDim.x * 256) >> 6;
    const float p  = pw[0];
    float sum = 0.f, sumsq = 0.f;

    int nA = gw, nB = gw + nwv;
    int cA = 0, svA = 0; float hA = 0.f;
    if (nA < NNODES) { cA = cnt[nA]; svA = (int)bucketU[nA * 64 + lane]; hA = h[nA * 64 + lane]; }
    int cB = 0, svB = 0; float hB = 0.f;
    if (nB < NNODES) { cB = cnt[nB]; svB = (int)bucketU[nB * 64 + lane]; hB = h[nB * 64 + lane]; }

    while (nA < NNODES) {
        const int  ca   = cA > CAP ? CAP : cA;
        const int  cb   = cB > CAP ? CAP : cB;
        const bool hasB = nB < NNODES;

        uint2 mvA[8], mvB[8];
        burst_load(M8, svA, ca, q, u, mvA);
        if (hasB) burst_load(M8, svB, cb, q, u, mvB);

        const int n2 = nA + 2 * nwv, n3 = nB + 2 * nwv;
        int c2 = 0, s2 = 0; float h2 = 0.f;
        int c3 = 0, s3 = 0; float h3 = 0.f;
        if (n2 < NNODES) { c2 = cnt[n2]; s2 = (int)bucketU[n2 * 64 + lane]; h2 = h[n2 * 64 + lane]; }
        if (n3 < NNODES) { c3 = cnt[n3]; s3 = (int)bucketU[n3 * 64 + lane]; h3 = h[n3 * 64 + lane]; }

        float A0, A1, A2, A3;
        unpack_acc(mvA, ca, q, u, M8, svA, A0, A1, A2, A3);
        combine_store(A0, A1, A2, A3, hA, p, lane, &h[nA * 64], sum, sumsq);

        if (hasB) {
            float B0, B1, B2, B3;
            unpack_acc(mvB, cb, q, u, M8, svB, B0, B1, B2, B3);
            combine_store(B0, B1, B2, B3, hB, p, lane, &h[nB * 64], sum, sumsq);
        }

        nA = n2; nB = n3;
        cA = c2; svA = s2; hA = h2;
        cB = c3; svB = s3; hB = h3;
    }
    atomicAdd(&ls[lane], sum);
    atomicAdd(&ls[64 + lane], sumsq);
    __syncthreads();
    if (tid < 128) atomicAdd(&stats[tid], ls[tid]);
}

// ---------------------------------------------------------------------------
// Kernel 4: BatchNorm (training-mode batch stats, biased var), float4.
// ---------------------------------------------------------------------------
__global__ __launch_bounds__(256) void bn_kernel(
    float4* __restrict__ h, const float* __restrict__ stats,
    const float* __restrict__ gamma, const float* __restrict__ beta)
{
    const int i  = blockIdx.x * 256 + threadIdx.x;
    const int c0 = (i & 15) * 4;
    const float inv = 1.0f / (float)NNODES;
    const float4 s1 = *(const float4*)&stats[c0];
    const float4 s2 = *(const float4*)&stats[64 + c0];
    const float4 gm = *(const float4*)&gamma[c0];
    const float4 bt = *(const float4*)&beta[c0];
    float4 v = h[i];
    float mu, var;
    mu = s1.x * inv; var = s2.x * inv - mu * mu; v.x = (v.x - mu) * (gm.x * rsqrtf(var + 1e-5f)) + bt.x;
    mu = s1.y * inv; var = s2.y * inv - mu * mu; v.y = (v.y - mu) * (gm.y * rsqrtf(var + 1e-5f)) + bt.y;
    mu = s1.z * inv; var = s2.z * inv - mu * mu; v.z = (v.z - mu) * (gm.z * rsqrtf(var + 1e-5f)) + bt.z;
    mu = s1.w * inv; var = s2.w * inv - mu * mu; v.w = (v.w - mu) * (gm.w * rsqrtf(var + 1e-5f)) + bt.w;
    h[i] = v;
}

extern "C" void kernel_launch(void* const* d_in, const int* in_sizes, int n_in,
                              void* d_out, int out_size, void* d_ws, size_t ws_size,
                              hipStream_t stream) {
    const float* x     = (const float*)d_in[0];
    const int*   ei    = (const int*)d_in[1];
    const float* W1    = (const float*)d_in[2];
    const float* b1    = (const float*)d_in[3];
    const float* W2    = (const float*)d_in[4];
    const float* b2    = (const float*)d_in[5];
    const float* Wr    = (const float*)d_in[6];
    const float* br    = (const float*)d_in[7];
    const float* pw    = (const float*)d_in[8];
    const float* gamma = (const float*)d_in[9];
    const float* beta  = (const float*)d_in[10];

    float* out = (float*)d_out;

    // workspace layout
    char* ws = (char*)d_ws;
    ushort* M16    = (ushort*)ws;                                  //  6.4 MB
    ushort* bucketU= (ushort*)(ws + 6400000);                      //  6.4 MB
    int*    cnt    = (int*)(ws + 12800000);                        //  200 KB
    float*  stats  = (float*)(ws + 13000000);                      //  512 B
    uint*   tbl    = (uint*)(ws + 13000512);                       //  41 KB

    prep_kernel<<<237, 256, 0, stream>>>(W1, b1, W2, b2, Wr, br, tbl, cnt, stats);
    fill_kernel<<<FILLB, 256, 0, stream>>>(ei, cnt, bucketU);
    mlp_root_kernel<<<256, 256, 0, stream>>>(x, tbl, M16, out);
    gather_prelu_stats_kernel<<<2048, 256, 0, stream>>>(cnt, bucketU, (const uint2*)M16, pw, out, stats);
    bn_kernel<<<3125, 256, 0, stream>>>((float4*)out, stats, gamma, beta);
}